// Round 1
// baseline (242.652 us; speedup 1.0000x reference)
//
#include <hip/hip_runtime.h>

// Shapes from reference: n=32, v=2, p2=64, w2=49, c_kv=256, topk=8
constexpr int N    = 32;
constexpr int V    = 2;
constexpr int P2   = 64;
constexpr int W2   = 49;
constexpr int CKV  = 256;
constexpr int TOPK = 8;

constexpr int BLK_ELEMS = W2 * CKV;      // 12544 floats per gathered KV block
constexpr int BLK_VEC4  = BLK_ELEMS / 4; // 3136 float4 per block (12544 % 4 == 0)
constexpr int NBLOCKS   = N * P2 * TOPK; // 16384 gather blocks

__global__ __launch_bounds__(256) void kvg_gather_kernel(
    const int* __restrict__ r_idx,   // (N, P2, TOPK), values in [0, V*P2)
    const float* __restrict__ kv,    // (N, V*P2, W2, CKV) flat
    float* __restrict__ out)         // (N, P2, TOPK, W2, CKV)
{
    const int bqk = blockIdx.x;            // which (b, q, k) triple
    const int b   = bqk / (P2 * TOPK);
    const int idx = r_idx[bqk];            // gather index into V*P2

    const float4* __restrict__ src = reinterpret_cast<const float4*>(
        kv + ((size_t)b * (V * P2) + (size_t)idx) * BLK_ELEMS);
    float4* __restrict__ dst = reinterpret_cast<float4*>(
        out + (size_t)bqk * BLK_ELEMS);

    // 3136 float4s, 256 threads: 12 full sweeps + 64-thread tail. Coalesced
    // 16B/lane loads and stores.
    for (int i = threadIdx.x; i < BLK_VEC4; i += 256) {
        dst[i] = src[i];
    }
}

extern "C" void kernel_launch(void* const* d_in, const int* in_sizes, int n_in,
                              void* d_out, int out_size, void* d_ws, size_t ws_size,
                              hipStream_t stream) {
    const int*   r_idx = (const int*)d_in[0];   // (N, P2, TOPK) int
    // d_in[1] = r_weight (float32) — unused by the reference output
    const float* kv    = (const float*)d_in[2]; // (N, V, P2, W2, CKV) float32
    float*       out   = (float*)d_out;

    kvg_gather_kernel<<<NBLOCKS, 256, 0, stream>>>(r_idx, kv, out);
}

// Round 3
// 218.758 us; speedup vs baseline: 1.1092x; 1.1092x over previous
//
#include <hip/hip_runtime.h>

// Shapes from reference: n=32, v=2, p2=64, w2=49, c_kv=256, topk=8
constexpr int N    = 32;
constexpr int V    = 2;
constexpr int P2   = 64;
constexpr int W2   = 49;
constexpr int CKV  = 256;
constexpr int TOPK = 8;

constexpr int BLK_ELEMS = W2 * CKV;      // 12544 floats per gathered KV block
constexpr int BLK_VEC4  = BLK_ELEMS / 4; // 3136 vec4 per block
constexpr int NBLOCKS   = N * P2 * TOPK; // 16384 gather blocks

// Native clang vector type: accepted by __builtin_nontemporal_store
// (HIP's float4 is a struct and is rejected).
typedef float fvec4 __attribute__((ext_vector_type(4)));

__global__ __launch_bounds__(256) void kvg_gather_kernel(
    const int* __restrict__ r_idx,   // (N, P2, TOPK), values in [0, V*P2)
    const float* __restrict__ kv,    // (N, V*P2, W2, CKV) flat
    float* __restrict__ out)         // (N, P2, TOPK, W2, CKV)
{
    const int bqk = blockIdx.x;            // which (b, q, k) triple
    const int b   = bqk / (P2 * TOPK);
    const int idx = r_idx[bqk];            // gather index into V*P2

    const fvec4* __restrict__ src = reinterpret_cast<const fvec4*>(
        kv + ((size_t)b * (V * P2) + (size_t)idx) * BLK_ELEMS);
    fvec4* __restrict__ dst = reinterpret_cast<fvec4*>(
        out + (size_t)bqk * BLK_ELEMS);

    // Coalesced 16B/lane copy. Loads: normal (kv is re-gathered ~4x on
    // average and fits in the 256MB Infinity Cache — keep it resident).
    // Stores: non-temporal (output never re-read; avoid write-allocate
    // evicting kv from L2/L3).
    for (int i = threadIdx.x; i < BLK_VEC4; i += 256) {
        fvec4 v = src[i];
        __builtin_nontemporal_store(v, dst + i);
    }
}

extern "C" void kernel_launch(void* const* d_in, const int* in_sizes, int n_in,
                              void* d_out, int out_size, void* d_ws, size_t ws_size,
                              hipStream_t stream) {
    const int*   r_idx = (const int*)d_in[0];   // (N, P2, TOPK) int
    // d_in[1] = r_weight (float32) — unused by the reference output
    const float* kv    = (const float*)d_in[2]; // (N, V, P2, W2, CKV) float32
    float*       out   = (float*)d_out;

    kvg_gather_kernel<<<NBLOCKS, 256, 0, stream>>>(r_idx, kv, out);
}

// Round 4
// 178.485 us; speedup vs baseline: 1.3595x; 1.2256x over previous
//
#include <hip/hip_runtime.h>

// Shapes from reference: n=32, v=2, p2=64, w2=49, c_kv=256, topk=8
constexpr int N    = 32;
constexpr int V    = 2;
constexpr int P2   = 64;
constexpr int W2   = 49;
constexpr int CKV  = 256;
constexpr int TOPK = 8;

constexpr int QK        = P2 * TOPK;       // 512 gathers per batch
constexpr int NGATHER   = N * QK;          // 16384 total gathers
constexpr int NSRC      = V * P2;          // 128 source blocks per batch
constexpr int NGROUP    = N * NSRC;        // 4096 (b, src) groups
constexpr int BLK_ELEMS = W2 * CKV;        // 12544 floats per KV block
constexpr int BLK_VEC4  = BLK_ELEMS / 4;   // 3136 vec4 per block

// Native clang vector type (accepted by __builtin_nontemporal_store).
typedef float fvec4 __attribute__((ext_vector_type(4)));

// ---- workspace layout (ints) ----
// cnt[NGROUP]      : gathers per (b,src) group
// fillpos[NGROUP]  : fill cursor per group
// start[NGROUP]    : CSR segment start per group
// lst[NGATHER]     : destination bqk ids, grouped by (b,src)
// cursor[1]        : global alloc cursor
constexpr int WS_CNT     = 0;
constexpr int WS_FILLPOS = WS_CNT + NGROUP;
constexpr int WS_START   = WS_FILLPOS + NGROUP;
constexpr int WS_LST     = WS_START + NGROUP;
constexpr int WS_CURSOR  = WS_LST + NGATHER;
constexpr int WS_INTS    = WS_CURSOR + 1;   // 28673 ints ≈ 112 KB

__global__ __launch_bounds__(256) void kvg_zero_kernel(int* ws) {
    int i = blockIdx.x * 256 + threadIdx.x;
    // zero cnt, fillpos, cursor (start/lst fully overwritten later)
    if (i < NGROUP) { ws[WS_CNT + i] = 0; ws[WS_FILLPOS + i] = 0; }
    if (i == 0) ws[WS_CURSOR] = 0;
}

__global__ __launch_bounds__(256) void kvg_count_kernel(
    const int* __restrict__ r_idx, int* ws) {
    int i = blockIdx.x * 256 + threadIdx.x;   // gather id in [0, NGATHER)
    if (i >= NGATHER) return;
    int b   = i / QK;
    int src = r_idx[i];                       // [0, NSRC)
    atomicAdd(&ws[WS_CNT + b * NSRC + src], 1);
}

__global__ __launch_bounds__(256) void kvg_alloc_kernel(int* ws) {
    int g = blockIdx.x * 256 + threadIdx.x;   // group id
    if (g >= NGROUP) return;
    int c = ws[WS_CNT + g];
    ws[WS_START + g] = atomicAdd(&ws[WS_CURSOR], c);
}

__global__ __launch_bounds__(256) void kvg_fill_kernel(
    const int* __restrict__ r_idx, int* ws) {
    int i = blockIdx.x * 256 + threadIdx.x;
    if (i >= NGATHER) return;
    int b   = i / QK;
    int src = r_idx[i];
    int g   = b * NSRC + src;
    int slot = atomicAdd(&ws[WS_FILLPOS + g], 1);
    ws[WS_LST + ws[WS_START + g] + slot] = i;
}

// One workgroup per (b, src) source block: stage 50KB block in LDS once,
// then fan-out NT-store it to all m gathered destinations. Each kv line
// crosses the L2->fabric boundary exactly once; writes are compulsory.
__global__ __launch_bounds__(256) void kvg_scatter_kernel(
    const float* __restrict__ kv,    // (N, NSRC, W2, CKV) flat
    const int* __restrict__ ws,
    float* __restrict__ out)         // (N, P2, TOPK, W2, CKV)
{
    __shared__ fvec4 lds[BLK_VEC4];  // 50176 B

    const int g = blockIdx.x;        // (b, src) group; source base = g*BLK_ELEMS
    const int m = ws[WS_CNT + g];
    if (m == 0) return;
    const int s = ws[WS_START + g];

    const fvec4* __restrict__ src = reinterpret_cast<const fvec4*>(
        kv + (size_t)g * BLK_ELEMS);
    for (int i = threadIdx.x; i < BLK_VEC4; i += 256)
        lds[i] = src[i];
    __syncthreads();

    for (int j = 0; j < m; ++j) {
        const int dst = ws[WS_LST + s + j];
        fvec4* __restrict__ d = reinterpret_cast<fvec4*>(
            out + (size_t)dst * BLK_ELEMS);
        for (int i = threadIdx.x; i < BLK_VEC4; i += 256)
            __builtin_nontemporal_store(lds[i], d + i);
    }
}

extern "C" void kernel_launch(void* const* d_in, const int* in_sizes, int n_in,
                              void* d_out, int out_size, void* d_ws, size_t ws_size,
                              hipStream_t stream) {
    const int*   r_idx = (const int*)d_in[0];   // (N, P2, TOPK) int
    // d_in[1] = r_weight (float32) — unused by the reference output
    const float* kv    = (const float*)d_in[2]; // (N, V, P2, W2, CKV) float32
    float*       out   = (float*)d_out;
    int*         ws    = (int*)d_ws;            // needs WS_INTS*4 ≈ 112 KB

    kvg_zero_kernel <<<(NGROUP  + 255) / 256, 256, 0, stream>>>(ws);
    kvg_count_kernel<<<(NGATHER + 255) / 256, 256, 0, stream>>>(r_idx, ws);
    kvg_alloc_kernel<<<(NGROUP  + 255) / 256, 256, 0, stream>>>(ws);
    kvg_fill_kernel <<<(NGATHER + 255) / 256, 256, 0, stream>>>(r_idx, ws);
    kvg_scatter_kernel<<<NGROUP, 256, 0, stream>>>(kv, ws, out);
}

// Round 6
// 176.056 us; speedup vs baseline: 1.3783x; 1.0138x over previous
//
#include <hip/hip_runtime.h>

// Shapes from reference: n=32, v=2, p2=64, w2=49, c_kv=256, topk=8
constexpr int N    = 32;
constexpr int V    = 2;
constexpr int P2   = 64;
constexpr int W2   = 49;
constexpr int CKV  = 256;
constexpr int TOPK = 8;

constexpr int QK        = P2 * TOPK;       // 512 gathers per batch
constexpr int NGATHER   = N * QK;          // 16384 total gathers
constexpr int NSRC      = V * P2;          // 128 source blocks per batch
constexpr int NGROUP    = N * NSRC;        // 4096 (b, src) groups
constexpr int BLK_ELEMS = W2 * CKV;        // 12544 floats per KV block
constexpr int BLK_VEC4  = BLK_ELEMS / 4;   // 3136 vec4 per block = 448 * 7

constexpr int CHUNKS      = 7;             // chunks per block
constexpr int CHUNK_VEC4  = BLK_VEC4 / CHUNKS; // 448 vec4 = 7168 B
constexpr int SCT_THREADS = 448;           // 7 waves; 1 vec4 per thread

// Native clang vector type (accepted by __builtin_nontemporal_store).
typedef float fvec4 __attribute__((ext_vector_type(4)));

// ---- workspace layout (ints) ----
constexpr int WS_CNT   = 0;                // cnt[NGROUP]
constexpr int WS_START = WS_CNT + NGROUP;  // start[NGROUP]
constexpr int WS_LST   = WS_START + NGROUP;// lst[NGATHER] destination ids
constexpr int WS_INTS  = WS_LST + NGATHER; // 24576 ints = 96 KB

// Single-workgroup CSR build: counts, segment alloc, fill — all in LDS.
__global__ __launch_bounds__(1024) void kvg_build_kernel(
    const int* __restrict__ r_idx, int* __restrict__ ws)
{
    __shared__ int cnt[NGROUP];
    __shared__ int seg[NGROUP];
    __shared__ int cursor;

    const int tid = threadIdx.x;
    for (int g = tid; g < NGROUP; g += 1024) cnt[g] = 0;
    if (tid == 0) cursor = 0;
    __syncthreads();

    // count (16 gathers per thread)
    int grp[NGATHER / 1024];
#pragma unroll
    for (int k = 0; k < NGATHER / 1024; ++k) {
        const int i = tid + k * 1024;
        const int g = (i / QK) * NSRC + r_idx[i];
        grp[k] = g;
        atomicAdd(&cnt[g], 1);
    }
    __syncthreads();

    // segment alloc (order-free: any segment placement / within-segment
    // order yields the same scatter output)
    for (int g = tid; g < NGROUP; g += 1024)
        seg[g] = atomicAdd(&cursor, cnt[g]);
    __syncthreads();

    // publish cnt/start ...
    for (int g = tid; g < NGROUP; g += 1024) {
        ws[WS_CNT + g]   = cnt[g];
        ws[WS_START + g] = seg[g];
    }
    // ... and ONLY THEN reuse seg[] as the fill cursor. Without this
    // barrier, atomicAdd below races with the start[] publish above
    // (round-5 bug: corrupted start -> unwritten lst slots kept 0xAA
    // poison -> negative dst -> OOB store -> device fault).
    __syncthreads();
#pragma unroll
    for (int k = 0; k < NGATHER / 1024; ++k) {
        const int i = tid + k * 1024;
        const int slot = atomicAdd(&seg[grp[k]], 1);
        ws[WS_LST + slot] = i;
    }
}

// One WG per (group, chunk): each thread holds one float4 of the source
// chunk in a register, then NT-stores it to all m destinations. Each kv
// line is read from HBM exactly once; writes are compulsory & streaming.
// No LDS, no __syncthreads, uniform work quantum (7 KB per fan-out step).
__global__ __launch_bounds__(SCT_THREADS) void kvg_scatter_kernel(
    const float* __restrict__ kv,    // (N, NSRC, W2, CKV) flat
    const int* __restrict__ ws,
    float* __restrict__ out)         // (N, P2, TOPK, W2, CKV)
{
    const int g = blockIdx.x / CHUNKS;
    const int c = blockIdx.x - g * CHUNKS;
    const int m = ws[WS_CNT + g];
    if (m == 0) return;
    const int s = ws[WS_START + g];

    const int chunk_off = c * CHUNK_VEC4 + threadIdx.x;   // vec4 offset in block
    const fvec4 v = reinterpret_cast<const fvec4*>(kv)
                        [(size_t)g * BLK_VEC4 + chunk_off];

    for (int j = 0; j < m; ++j) {
        const int dst = ws[WS_LST + s + j];               // wave-uniform scalar load
        __builtin_nontemporal_store(
            v, reinterpret_cast<fvec4*>(out) + (size_t)dst * BLK_VEC4 + chunk_off);
    }
}

extern "C" void kernel_launch(void* const* d_in, const int* in_sizes, int n_in,
                              void* d_out, int out_size, void* d_ws, size_t ws_size,
                              hipStream_t stream) {
    const int*   r_idx = (const int*)d_in[0];   // (N, P2, TOPK) int
    // d_in[1] = r_weight (float32) — unused by the reference output
    const float* kv    = (const float*)d_in[2]; // (N, V, P2, W2, CKV) float32
    float*       out   = (float*)d_out;
    int*         ws    = (int*)d_ws;            // needs WS_INTS*4 = 96 KB

    kvg_build_kernel  <<<1, 1024, 0, stream>>>(r_idx, ws);
    kvg_scatter_kernel<<<NGROUP * CHUNKS, SCT_THREADS, 0, stream>>>(kv, ws, out);
}

// Round 7
// 151.516 us; speedup vs baseline: 1.6015x; 1.1620x over previous
//
#include <hip/hip_runtime.h>

// Shapes from reference: n=32, v=2, p2=64, w2=49, c_kv=256, topk=8
constexpr int N    = 32;
constexpr int V    = 2;
constexpr int P2   = 64;
constexpr int W2   = 49;
constexpr int CKV  = 256;
constexpr int TOPK = 8;

constexpr int QK        = P2 * TOPK;       // 512 gathers per batch
constexpr int NSRC      = V * P2;          // 128 source blocks per batch
constexpr int NGROUP    = N * NSRC;        // 4096 (b, src) groups
constexpr int BLK_ELEMS = W2 * CKV;        // 12544 floats per KV block
constexpr int BLK_VEC4  = BLK_ELEMS / 4;   // 3136 vec4 per block = 448 * 7

constexpr int CHUNKS      = 7;                 // chunks per block
constexpr int CHUNK_VEC4  = BLK_VEC4 / CHUNKS; // 448 vec4 = 7168 B
constexpr int SCT_THREADS = 448;               // 7 waves; 1 vec4 per thread

// Native clang vector type (accepted by __builtin_nontemporal_store).
typedef float fvec4 __attribute__((ext_vector_type(4)));

// Fused inverse-gather scatter. One WG per (group, chunk):
//  1. scan the batch's 512 r_idx entries (64KB total across the whole grid,
//     L2-resident; ~1 coalesced load per thread) and collect the m
//     destinations whose index == this group's src block, via LDS atomics;
//  2. each thread holds one float4 of the source chunk in a register;
//  3. NT-store the chunk to all m destinations (output is never re-read;
//     nt avoids write-allocate evicting kv from L2/L3).
// Each kv line crosses HBM exactly once; writes are compulsory & streaming.
// No CSR build kernel, no workspace, no serial single-CU prologue.
__global__ __launch_bounds__(SCT_THREADS) void kvg_scatter_kernel(
    const int* __restrict__ r_idx,   // (N, P2, TOPK) -> values in [0, NSRC)
    const float* __restrict__ kv,    // (N, NSRC, W2, CKV) flat
    float* __restrict__ out)         // (N, P2, TOPK, W2, CKV)
{
    __shared__ int dsts[QK];         // worst-case all 512 gathers hit one src
    __shared__ int cnt;

    const int g   = blockIdx.x / CHUNKS;   // (b, src) group
    const int c   = blockIdx.x - g * CHUNKS;
    const int b   = g / NSRC;
    const int src = g - b * NSRC;

    if (threadIdx.x == 0) cnt = 0;
    __syncthreads();

    // Issue the chunk load early; it is independent of the scan below and
    // its ~500-cycle HBM latency hides under the index scan + barrier.
    const int chunk_off = c * CHUNK_VEC4 + threadIdx.x;  // vec4 offset in block
    const fvec4 v = reinterpret_cast<const fvec4*>(kv)
                        [(size_t)g * BLK_VEC4 + chunk_off];

    // Inverse-index scan: which gathers of batch b want source block `src`?
    for (int i = threadIdx.x; i < QK; i += SCT_THREADS) {
        if (r_idx[b * QK + i] == src)
            dsts[atomicAdd(&cnt, 1)] = b * QK + i;
    }
    __syncthreads();
    const int m = cnt;

    for (int j = 0; j < m; ++j) {
        const int dst = dsts[j];     // wave-uniform LDS broadcast
        __builtin_nontemporal_store(
            v, reinterpret_cast<fvec4*>(out) + (size_t)dst * BLK_VEC4 + chunk_off);
    }
}

extern "C" void kernel_launch(void* const* d_in, const int* in_sizes, int n_in,
                              void* d_out, int out_size, void* d_ws, size_t ws_size,
                              hipStream_t stream) {
    const int*   r_idx = (const int*)d_in[0];   // (N, P2, TOPK) int
    // d_in[1] = r_weight (float32) — unused by the reference output
    const float* kv    = (const float*)d_in[2]; // (N, V, P2, W2, CKV) float32
    float*       out   = (float*)d_out;

    kvg_scatter_kernel<<<NGROUP * CHUNKS, SCT_THREADS, 0, stream>>>(r_idx, kv, out);
}